// Round 14
// baseline (5522.483 us; speedup 1.0000x reference)
//
#include <hip/hip_runtime.h>
#include <hip/hip_fp16.h>
#include <cstddef>
#include <cstdint>

#define B_  256
#define T_  512
#define D_  128
#define H_  256
#define G3_ 768
#define C_  10

typedef _Float16 f16x8 __attribute__((ext_vector_type(8)));
typedef float    f32x4 __attribute__((ext_vector_type(4)));

__device__ __forceinline__ float sigmoid_f(float x) {
    return 1.0f / (1.0f + __expf(-x));
}
__device__ __forceinline__ float tanh_f(float x) {
    return 1.0f - 2.0f / (__expf(2.0f * x) + 1.0f);
}

__device__ __forceinline__ unsigned int packh2(float a, float b) {
    unsigned short lo = __half_as_ushort(__float2half(a));   // k even -> lo16
    unsigned short hi = __half_as_ushort(__float2half(b));   // k odd  -> hi16
    return (unsigned int)lo | ((unsigned int)hi << 16);
}

// ---------------------------------------------------------------------------
// Chunk-granularity flag protocol (R4/R6-proven release/acquire shape; used
// 8-9 times per block TOTAL, not per step -- R6 proved per-step sync costs
// 5.5us/step; at chunk granularity the same machinery is ~0.1us/step).
// All spins guard-bounded: worst case = wrong answer, never a hang.
// ---------------------------------------------------------------------------
__device__ __forceinline__ void block_wait(int* flag, int target) {
    if (threadIdx.x == 0) {
        int grd = 0;
        while (__hip_atomic_load(flag, __ATOMIC_ACQUIRE,
                                 __HIP_MEMORY_SCOPE_AGENT) < target &&
               ++grd < (1 << 22)) {}
    }
    __syncthreads();
}
__device__ __forceinline__ void block_post(int* flag) {
    __threadfence();
    __syncthreads();
    if (threadIdx.x == 0)
        __hip_atomic_fetch_add(flag, 1, __ATOMIC_RELEASE,
                               __HIP_MEMORY_SCOPE_AGENT);
}

// ---------------------------------------------------------------------------
// Pack Whh[3H][H] fp32 -> f16 MFMA B-fragment stream for the scan.
// (unchanged, harness-verified layout)
// ---------------------------------------------------------------------------
__global__ void k_pack_whh(const float* __restrict__ Whh, uint4* __restrict__ Wl) {
    const int wnt = blockIdx.x;          // w*6 + nt
    const int w  = wnt / 6;
    const int nt = wnt % 6;
    const int t  = threadIdx.x;
    const int kt = t >> 6;
    const int l  = t & 63;
    const int g  = nt >> 1;
    const int n  = g * 256 + w * 32 + (nt & 1) * 16 + (l & 15);
    const int k0 = kt * 32 + (l >> 4) * 8;
    const float* row = Whh + (size_t)n * H_ + k0;
    uint4 u;
    u.x = packh2(row[0], row[1]);
    u.y = packh2(row[2], row[3]);
    u.z = packh2(row[4], row[5]);
    u.w = packh2(row[6], row[7]);
    Wl[(size_t)wnt * 512 + t] = u;
}

// ---------------------------------------------------------------------------
// Pack Wih[768][K] fp32 -> f16 B-fragments for the gi GEMM. (unchanged)
// ---------------------------------------------------------------------------
__global__ void k_pack_wih(const float* __restrict__ W, uint4* __restrict__ Wp,
                           int K) {
    const int KT = K >> 5;
    const int f  = blockIdx.x * 4 + (threadIdx.x >> 6);
    const int l  = threadIdx.x & 63;
    const int ntile = f / KT;
    const int kt    = f - ntile * KT;
    const int n  = ntile * 16 + (l & 15);
    const int k0 = kt * 32 + (l >> 4) * 8;
    const float* row = W + (size_t)n * K + k0;
    uint4 u;
    u.x = packh2(row[0], row[1]);
    u.y = packh2(row[2], row[3]);
    u.z = packh2(row[4], row[5]);
    u.w = packh2(row[6], row[7]);
    Wp[(size_t)f * 64 + l] = u;
}

// ---------------------------------------------------------------------------
// One gemm tile-unit (R13's verified in-fused shape): 512 thr, 256 rows x
// 128 cols, runtime KT. A f32 (x) or f16 (h1c). C f32 normal layout.
// ---------------------------------------------------------------------------
__device__ void gemm_unit(
    const void* __restrict__ A, long Abstride, int tcShift, int aIsF16,
    const uint4* __restrict__ Wp, const float* __restrict__ bias,
    float* __restrict__ C, int K, int v, int n0)
{
    const int tid = threadIdx.x;
    const int w  = tid >> 6;
    const int l  = tid & 63;
    const int c  = l & 15;
    const int g4 = l >> 4;
    const int m0 = v * 256 + w * 32;
    const int KT = K >> 5;
    const int mask = (1 << tcShift) - 1;

    const int mg0 = m0 + c;
    const int mg1 = mg0 + 16;
    const size_t aoff0 = (size_t)(mg0 >> tcShift) * Abstride
                       + (size_t)(mg0 & mask) * K + g4 * 8;
    const size_t aoff1 = (size_t)(mg1 >> tcShift) * Abstride
                       + (size_t)(mg1 & mask) * K + g4 * 8;
    const float*    Af0 = (const float*)A    + aoff0;
    const float*    Af1 = (const float*)A    + aoff1;
    const _Float16* Ah0 = (const _Float16*)A + aoff0;
    const _Float16* Ah1 = (const _Float16*)A + aoff1;

    const uint4* Wb = Wp + (size_t)((n0 >> 4) * KT) * 64 + l;

    f32x4 acc[2][8] = {};

    for (int kt = 0; kt < KT; kt++) {
        f16x8 a0, a1;
        if (aIsF16) {
            a0 = *(const f16x8*)(Ah0 + kt * 32);
            a1 = *(const f16x8*)(Ah1 + kt * 32);
        } else {
            float4 lo = *(const float4*)(Af0 + kt * 32);
            float4 hi = *(const float4*)(Af0 + kt * 32 + 4);
            a0[0] = (_Float16)lo.x; a0[1] = (_Float16)lo.y;
            a0[2] = (_Float16)lo.z; a0[3] = (_Float16)lo.w;
            a0[4] = (_Float16)hi.x; a0[5] = (_Float16)hi.y;
            a0[6] = (_Float16)hi.z; a0[7] = (_Float16)hi.w;
            lo = *(const float4*)(Af1 + kt * 32);
            hi = *(const float4*)(Af1 + kt * 32 + 4);
            a1[0] = (_Float16)lo.x; a1[1] = (_Float16)lo.y;
            a1[2] = (_Float16)lo.z; a1[3] = (_Float16)lo.w;
            a1[4] = (_Float16)hi.x; a1[5] = (_Float16)hi.y;
            a1[6] = (_Float16)hi.z; a1[7] = (_Float16)hi.w;
        }
#pragma unroll
        for (int ct = 0; ct < 8; ct++) {
            uint4 wf = Wb[(size_t)(ct * KT + kt) * 64];
            acc[0][ct] = __builtin_amdgcn_mfma_f32_16x16x32_f16(
                a0, __builtin_bit_cast(f16x8, wf), acc[0][ct], 0, 0, 0);
            acc[1][ct] = __builtin_amdgcn_mfma_f32_16x16x32_f16(
                a1, __builtin_bit_cast(f16x8, wf), acc[1][ct], 0, 0, 0);
        }
    }

#pragma unroll
    for (int ct = 0; ct < 8; ct++) {
        const int n = n0 + ct * 16 + c;
        const float bv = bias[n];
#pragma unroll
        for (int rt = 0; rt < 2; rt++) {
#pragma unroll
            for (int rg = 0; rg < 4; rg++) {
                const int m = m0 + rt * 16 + g4 * 4 + rg;
                C[(size_t)m * G3_ + n] = acc[rt][ct][rg] + bv;
            }
        }
    }
}

// ---------------------------------------------------------------------------
// Persistent scan role. EXACT R4/R10 step loop (2.785 us/step; VGPR 124);
// weight staging hoisted out of the chunk loop; h carried in registers/LDS
// across chunks (no per-chunk h_state round trip). Gates at CHUNK tops only.
// ---------------------------------------------------------------------------
__device__ void scan_role(
    int isL0, int b0,
    const float* __restrict__ giA, const float* __restrict__ giB,
    const uint4* __restrict__ Wpk, const float* __restrict__ bhh,
    _Float16* __restrict__ h1cA, _Float16* __restrict__ h1cB,
    float* __restrict__ hstFinal,
    int Tc, int nChunks, int UPC,
    int* C0, int* C1, int* G0, int* G1,
    uint4 (&lds_w)[8192], _Float16 (&lds_h)[2][16][264])
{
    const int tid = threadIdx.x;
    const int w  = tid >> 6;       // wave 0..7
    const int l  = tid & 63;
    const int c  = l & 15;
    const int g4 = l >> 4;         // 0..3

    // ---- stage LDS-resident weight frags ONCE (nt 4,5 of every wave) ------
#pragma unroll
    for (int i = 0; i < 16; i++) {
        int idx = i * 512 + tid;
        lds_w[idx] = Wpk[(size_t)(idx >> 10) * 3072 + 2048 + (idx & 1023)];
    }

    uint4 wreg[32];                // remat'd per step by allocator (proven)
#pragma unroll
    for (int nt = 0; nt < 4; nt++)
#pragma unroll
        for (int kt = 0; kt < 8; kt++)
            wreg[nt * 8 + kt] = Wpk[(size_t)((w * 6 + nt) * 8 + kt) * 64 + l];

    const int jA = w * 32 + c;
    const float br0 = bhh[jA],       br1 = bhh[jA + 16];
    const float bz0 = bhh[256 + jA], bz1 = bhh[256 + jA + 16];
    const float bn0 = bhh[512 + jA], bn1 = bhh[512 + jA + 16];

    float hreg[4][2];
#pragma unroll
    for (int r = 0; r < 4; r++) {
        const int m = g4 * 4 + r;
        hreg[r][0] = 0.0f;
        hreg[r][1] = 0.0f;
        lds_h[0][m][jA]      = (_Float16)0.0f;
        lds_h[0][m][jA + 16] = (_Float16)0.0f;
    }
    __syncthreads();

    int cur = 0;
    for (int ck = 0; ck < nChunks; ++ck) {
        // ---- chunk gates --------------------------------------------------
        if (isL0) {
            block_wait(G0, UPC * (ck + 1));            // gi0(ck) ready
            if (ck >= 2) block_wait(G1, UPC * (ck - 1)); // h1c[ck&1] free
        } else {
            block_wait(G1, UPC * (ck + 1));            // gi1(ck) ready
        }
        const float* gi = ((ck & 1) ? giB : giA) + (size_t)b0 * Tc * G3_;
        _Float16* oseq = isL0
            ? ((ck & 1) ? h1cB : h1cA) + (size_t)b0 * Tc * H_ : nullptr;

        for (int tt = 0; tt < Tc; ++tt) {
            unsigned wb = (unsigned)(w * 1024 + l);
            asm volatile("" : "+v"(wb));               // LICM barrier

            float gic[4][6];
#pragma unroll
            for (int r = 0; r < 4; r++) {
                const float* gp = gi + ((size_t)(g4 * 4 + r) * Tc + tt) * G3_ + jA;
#pragma unroll
                for (int gg = 0; gg < 3; gg++) {
                    gic[r][gg * 2 + 0] = gp[gg * 256];
                    gic[r][gg * 2 + 1] = gp[gg * 256 + 16];
                }
            }

            f32x4 acc[6] = {};
#pragma unroll
            for (int kt = 0; kt < 8; kt++) {
                f16x8 a = *(const f16x8*)&lds_h[cur][c][kt * 32 + g4 * 8];
#pragma unroll
                for (int nt = 0; nt < 4; nt++)
                    acc[nt] = __builtin_amdgcn_mfma_f32_16x16x32_f16(
                        a, __builtin_bit_cast(f16x8, wreg[nt * 8 + kt]), acc[nt], 0, 0, 0);
                uint4 u4 = lds_w[wb + kt * 64];
                acc[4] = __builtin_amdgcn_mfma_f32_16x16x32_f16(
                    a, __builtin_bit_cast(f16x8, u4), acc[4], 0, 0, 0);
                uint4 u5 = lds_w[wb + (8 + kt) * 64];
                acc[5] = __builtin_amdgcn_mfma_f32_16x16x32_f16(
                    a, __builtin_bit_cast(f16x8, u5), acc[5], 0, 0, 0);
            }

#pragma unroll
            for (int r = 0; r < 4; r++) {
                const int m = g4 * 4 + r;
#pragma unroll
                for (int jj = 0; jj < 2; jj++) {
                    float rg = sigmoid_f(gic[r][jj]     + acc[jj][r]     + (jj ? br1 : br0));
                    float zg = sigmoid_f(gic[r][2 + jj] + acc[2 + jj][r] + (jj ? bz1 : bz0));
                    float ng = tanh_f(gic[r][4 + jj] +
                                      rg * (acc[4 + jj][r] + (jj ? bn1 : bn0)));
                    float hn = (1.0f - zg) * ng + zg * hreg[r][jj];
                    hreg[r][jj] = hn;
                    _Float16 hq = (_Float16)hn;
                    lds_h[cur ^ 1][m][jA + jj * 16] = hq;
                    if (oseq)
                        oseq[((size_t)m * Tc + tt) * H_ + jA + jj * 16] = hq;
                }
            }
            __syncthreads();
            cur ^= 1;
        }
        // ---- chunk complete: release h1c (L0) / gi1 buffer (L1) ----------
        block_post(isL0 ? C0 : C1);
    }

    if (!isL0) {
        float* hp = hstFinal + (size_t)b0 * H_;
#pragma unroll
        for (int r = 0; r < 4; r++) {
            const int m = g4 * 4 + r;
            hp[(size_t)m * H_ + jA]      = hreg[r][0];
            hp[(size_t)m * H_ + jA + 16] = hreg[r][1];
        }
    }
}

// ---------------------------------------------------------------------------
// PERSISTENT DATAFLOW KERNEL. 256 blocks x 512 thr, 148 KB LDS -> exactly
// 1 block/CU -> all co-resident (spin-safe). Blocks 0..15: scan0 (all
// chunks, continuous). 16..31: scan1 (lags 1 chunk). 32..255: 224 workers
// producing gi0 (from x, prefetched 1-2 chunks ahead) and gi1 (from h1c,
// 1 chunk behind scan0). Replaces 9 fused + 8 gemm1 + 1 gemm0 launches:
// eliminates 8x9us launch overhead AND the 213us serialized gemm1 tail.
// ---------------------------------------------------------------------------
__global__ __launch_bounds__(512, 2) void k_gru_persist(
    const float* __restrict__ x,
    const uint4* __restrict__ wl0, const uint4* __restrict__ wl1,
    const uint4* __restrict__ wp0, const uint4* __restrict__ wp1,
    const float* __restrict__ bih0, const float* __restrict__ bih1,
    const float* __restrict__ bhh0, const float* __restrict__ bhh1,
    float* __restrict__ gi0A, float* __restrict__ gi0B,
    float* __restrict__ gi1A, float* __restrict__ gi1B,
    _Float16* __restrict__ h1cA, _Float16* __restrict__ h1cB,
    float* __restrict__ hst1, int* __restrict__ flags,
    int Tc, int tcShift, int nChunks)
{
    __shared__ __align__(16) uint4    lds_w[8192];        // 128 KB
    __shared__ __align__(16) _Float16 lds_h[2][16][264];  // 16.5 KB

    int* C0 = flags;        // scan0 chunks done (16/chunk)
    int* C1 = flags + 16;   // scan1 chunks done (16/chunk)
    int* G0 = flags + 32;   // gemm0 units done (UPC/chunk)
    int* G1 = flags + 48;   // gemm1 units done (UPC/chunk)
    const int UPC = (B_ * Tc / 256) * 6;

    const int blk = blockIdx.x;
    if (blk < 16) {
        scan_role(1, blk * 16, gi0A, gi0B, wl0, bhh0, h1cA, h1cB, nullptr,
                  Tc, nChunks, UPC, C0, C1, G0, G1, lds_w, lds_h);
    } else if (blk < 32) {
        scan_role(0, (blk - 16) * 16, gi1A, gi1B, wl1, bhh1, nullptr, nullptr,
                  hst1, Tc, nChunks, UPC, C0, C1, G0, G1, lds_w, lds_h);
    } else {
        const int q = blk - 32;    // worker 0..223
        for (int p = 0; p <= nChunks; ++p) {
            if (p == 0) {
                for (int u = q; u < UPC; u += 224) {          // gemm0(0)
                    gemm_unit(x, (long)T_ * D_, tcShift, 0, wp0, bih0,
                              gi0A, D_, u / 6, (u % 6) * 128);
                    block_post(G0);
                }
                if (nChunks > 1)
                    for (int u = q; u < UPC; u += 224) {      // gemm0(1)
                        gemm_unit(x + (size_t)Tc * D_, (long)T_ * D_, tcShift,
                                  0, wp0, bih0, gi0B, D_, u / 6, (u % 6) * 128);
                        block_post(G0);
                    }
            } else {
                block_wait(C0, 16 * p);                       // h1c(p-1) ready
                if (p >= 3) block_wait(C1, 16 * (p - 2));     // gi1 buf free
                const _Float16* hsrc = ((p - 1) & 1) ? h1cB : h1cA;
                float* g1dst = ((p - 1) & 1) ? gi1B : gi1A;
                for (int u = q; u < UPC; u += 224) {          // gemm1(p-1)
                    gemm_unit(hsrc, (long)Tc * H_, tcShift, 1, wp1, bih1,
                              g1dst, H_, u / 6, (u % 6) * 128);
                    block_post(G1);
                }
                if (p + 1 <= nChunks - 1) {
                    float* g0dst = ((p + 1) & 1) ? gi0B : gi0A;
                    const float* xsrc = x + (size_t)(p + 1) * Tc * D_;
                    for (int u = q; u < UPC; u += 224) {      // gemm0(p+1)
                        gemm_unit(xsrc, (long)T_ * D_, tcShift, 0, wp0, bih0,
                                  g0dst, D_, u / 6, (u % 6) * 128);
                        block_post(G0);
                    }
                }
            }
        }
    }
}

// ---------------------------------------------------------------------------
__global__ void k_fc(const float* __restrict__ h, const float* __restrict__ Wfc,
                     const float* __restrict__ bfc, float* __restrict__ out)
{
    int idx = blockIdx.x * blockDim.x + threadIdx.x;
    if (idx >= B_ * C_) return;
    int b = idx / C_, c = idx % C_;
    const float* hp = h + (size_t)b * H_;
    const float* wp = Wfc + (size_t)c * H_;
    float s = bfc[c];
#pragma unroll 4
    for (int k = 0; k < H_; k++) s = fmaf(hp[k], wp[k], s);
    out[idx] = s;
}

// ---------------------------------------------------------------------------
extern "C" void kernel_launch(void* const* d_in, const int* in_sizes, int n_in,
                              void* d_out, int out_size, void* d_ws, size_t ws_size,
                              hipStream_t stream)
{
    const float* x    = (const float*)d_in[0];
    const float* Wih0 = (const float*)d_in[1];
    const float* Whh0 = (const float*)d_in[2];
    const float* bih0 = (const float*)d_in[3];
    const float* bhh0 = (const float*)d_in[4];
    const float* Wih1 = (const float*)d_in[5];
    const float* Whh1 = (const float*)d_in[6];
    const float* bih1 = (const float*)d_in[7];
    const float* bhh1 = (const float*)d_in[8];
    const float* Wfc  = (const float*)d_in[9];
    const float* bfc  = (const float*)d_in[10];
    float* out = (float*)d_out;

    const size_t wlBytes  = (size_t)48 * 512 * sizeof(uint4);    // 393,216 B
    const size_t wp0Bytes = (size_t)48 * 4 * 64 * sizeof(uint4); // 196,608 B
    const size_t wp1Bytes = (size_t)48 * 8 * 64 * sizeof(uint4); // 393,216 B
    const size_t flBytes  = 64 * sizeof(int);

    // ---- T-chunk: 64 (R10 sweet spot); 4 gi bufs (gi0 dbuf + gi1 dbuf) ----
    const size_t fixedB = 2 * wlBytes + wp0Bytes + wp1Bytes + flBytes
                        + (size_t)B_ * H_ * 4 + 16384;
    int Tc = 64, tcShift = 6;
    while (Tc > 1) {
        size_t need = fixedB
                    + 4 * (size_t)B_ * Tc * G3_ * 4    // gi0A/B, gi1A/B (f32)
                    + 2 * (size_t)B_ * Tc * H_ * 2;    // h1cA/B (f16)
        if (need <= ws_size) break;
        Tc >>= 1; tcShift--;
    }
    const int nChunks = T_ / Tc;

    char* ws = (char*)d_ws;
    size_t off = 0;
    auto alloc = [&](size_t bytes) { char* p = ws + off; off += (bytes + 255) & ~(size_t)255; return p; };
    float*    gi0A = (float*)alloc((size_t)B_ * Tc * G3_ * 4);
    float*    gi0B = (float*)alloc((size_t)B_ * Tc * G3_ * 4);
    float*    gi1A = (float*)alloc((size_t)B_ * Tc * G3_ * 4);
    float*    gi1B = (float*)alloc((size_t)B_ * Tc * G3_ * 4);
    _Float16* h1cA = (_Float16*)alloc((size_t)B_ * Tc * H_ * 2);
    _Float16* h1cB = (_Float16*)alloc((size_t)B_ * Tc * H_ * 2);
    uint4* wl0  = (uint4*)alloc(wlBytes);
    uint4* wl1  = (uint4*)alloc(wlBytes);
    uint4* wp0  = (uint4*)alloc(wp0Bytes);
    uint4* wp1  = (uint4*)alloc(wp1Bytes);
    float* hst1 = (float*)alloc((size_t)B_ * H_ * 4);
    int*   flags = (int*)alloc(flBytes);

    hipMemsetAsync(flags, 0, flBytes, stream);

    k_pack_whh<<<48, 512, 0, stream>>>(Whh0, wl0);
    k_pack_whh<<<48, 512, 0, stream>>>(Whh1, wl1);
    k_pack_wih<<<48, 256, 0, stream>>>(Wih0, wp0, D_);   // KT=4 -> 192 frags
    k_pack_wih<<<96, 256, 0, stream>>>(Wih1, wp1, H_);   // KT=8 -> 384 frags

    k_gru_persist<<<256, 512, 0, stream>>>(
        x, wl0, wl1, wp0, wp1, bih0, bih1, bhh0, bhh1,
        gi0A, gi0B, gi1A, gi1B, h1cA, h1cB, hst1, flags,
        Tc, tcShift, nChunks);

    k_fc<<<10, 256, 0, stream>>>(hst1, Wfc, bfc, out);
}